// Round 1
// baseline (347.866 us; speedup 1.0000x reference)
//
#include <hip/hip_runtime.h>
#include <hip/hip_bf16.h>
#include <stdint.h>

typedef __attribute__((ext_vector_type(8))) __bf16 bf16x8;
typedef __attribute__((ext_vector_type(4))) __bf16 bf16x4;
typedef __attribute__((ext_vector_type(4))) float f32x4;

#define AS1 __attribute__((address_space(1)))
#define AS3 __attribute__((address_space(3)))

__device__ __forceinline__ void load_lds16(const void* g, void* l) {
    __builtin_amdgcn_global_load_lds((const AS1 void*)g, (AS3 void*)l, 16, 0, 0);
}

constexpr float SCALE = 0.125f;  // 64^-0.5

// ---------------------------------------------------------------------------
// elementwise fp32 -> bf16 convert (vectorized float4 in, 4x bf16 out)
__global__ void cvt_x(const float4* __restrict__ x, bf16x4* __restrict__ o, int n4) {
    int i = blockIdx.x * blockDim.x + threadIdx.x;
    if (i >= n4) return;
    float4 v = x[i];
    bf16x4 r;
    r[0] = (__bf16)v.x; r[1] = (__bf16)v.y; r[2] = (__bf16)v.z; r[3] = (__bf16)v.w;
    o[i] = r;
}

// ---------------------------------------------------------------------------
// transpose + convert: src fp32 [R][C] -> dst bf16 [C][R]
__global__ void tconv(const float* __restrict__ src, __bf16* __restrict__ dst,
                      int R, int C) {
    __shared__ float tile[32][33];
    int c0 = blockIdx.x * 32, r0 = blockIdx.y * 32;
    int tx = threadIdx.x, ty = threadIdx.y;  // 32 x 8
    #pragma unroll
    for (int i = 0; i < 32; i += 8)
        tile[ty + i][tx] = src[(size_t)(r0 + ty + i) * C + c0 + tx];
    __syncthreads();
    #pragma unroll
    for (int i = 0; i < 32; i += 8)
        dst[(size_t)(c0 + ty + i) * R + r0 + tx] = (__bf16)tile[tx][ty + i];
}

// ---------------------------------------------------------------------------
// 128x128 bf16 GEMM, Bt is [N][K] (pre-transposed). C = A @ Bt^T + bias.
// MODE 0: scatter into Q/K/V [3][32][2048][64] bf16 (outp = q base)
// MODE 1: plain fp32 [M][Nn] output
template <int MODE>
__global__ __launch_bounds__(256)
void gemm128(const __bf16* __restrict__ A, const __bf16* __restrict__ Bt,
             const float* __restrict__ bias, void* __restrict__ outp,
             int M, int Nn, int K) {
    __shared__ __bf16 As[128][32];
    __shared__ __bf16 Bs[128][32];
    const int t = threadIdx.x;
    const int w = t >> 6, l = t & 63;
    const int lrow = l & 15, lhi = l >> 4;
    const int wr = (w >> 1) * 64, wc = (w & 1) * 64;
    const int m0 = blockIdx.y * 128, n0 = blockIdx.x * 128;

    f32x4 acc[4][4] = {};

    const int sr = t >> 2, sc = (t & 3) * 8;  // staging: row t/4, 8 elems
    const __bf16* ag = A + (size_t)(m0 + sr) * K + sc;
    const __bf16* bg = Bt + (size_t)(n0 + sr) * K + sc;

    for (int kt = 0; kt < K; kt += 32) {
        load_lds16(ag, &As[sr][sc]);
        load_lds16(ag + (size_t)64 * K, &As[64 + sr][sc]);
        load_lds16(bg, &Bs[sr][sc]);
        load_lds16(bg + (size_t)64 * K, &Bs[64 + sr][sc]);
        ag += 32; bg += 32;
        __syncthreads();
        bf16x8 af[4], bfv[4];
        #pragma unroll
        for (int i = 0; i < 4; ++i)
            af[i] = *(const bf16x8*)(&As[wr + i * 16 + lrow][lhi * 8]);
        #pragma unroll
        for (int j = 0; j < 4; ++j)
            bfv[j] = *(const bf16x8*)(&Bs[wc + j * 16 + lrow][lhi * 8]);
        #pragma unroll
        for (int i = 0; i < 4; ++i)
            #pragma unroll
            for (int j = 0; j < 4; ++j)
                acc[i][j] = __builtin_amdgcn_mfma_f32_16x16x32_bf16(
                    af[i], bfv[j], acc[i][j], 0, 0, 0);
        __syncthreads();
    }

    #pragma unroll
    for (int i = 0; i < 4; ++i)
        #pragma unroll
        for (int j = 0; j < 4; ++j)
            #pragma unroll
            for (int r = 0; r < 4; ++r) {
                int row = m0 + wr + i * 16 + lhi * 4 + r;  // D: row=(l>>4)*4+r
                int col = n0 + wc + j * 16 + lrow;         // D: col=l&15
                float val = acc[i][j][r] + bias[col];
                if (MODE == 0) {
                    int which = col >> 10;          // 0=q 1=k 2=v
                    int h = (col >> 6) & 15;
                    int d = col & 63;
                    int b = row >> 11;
                    int n = row & 2047;
                    ((__bf16*)outp)[(size_t)which * (32 * 2048 * 64) +
                                    (((size_t)((b << 4) + h)) * 2048 + n) * 64 + d] =
                        (__bf16)val;
                } else {
                    ((float*)outp)[(size_t)row * Nn + col] = val;
                }
            }
}

// ---------------------------------------------------------------------------
// transpose V: [32][2048][64] -> Vt [32][64][2048] (bf16)
__global__ __launch_bounds__(256)
void vtrans(const __bf16* __restrict__ v, __bf16* __restrict__ vt) {
    __shared__ __bf16 tile[64][72];  // pad to dodge bank conflicts
    const int bh = blockIdx.y, n0 = blockIdx.x * 64;
    const int t = threadIdx.x;
    const int r = t >> 2, c0 = (t & 3) * 16;
    const __bf16* src = v + ((size_t)bh * 2048 + n0) * 64;
    *(bf16x8*)&tile[r][c0]     = *(const bf16x8*)(src + (size_t)r * 64 + c0);
    *(bf16x8*)&tile[r][c0 + 8] = *(const bf16x8*)(src + (size_t)r * 64 + c0 + 8);
    __syncthreads();
    __bf16* dst = vt + ((size_t)bh * 64 + r) * 2048 + n0 + c0;
    #pragma unroll
    for (int i = 0; i < 16; ++i) dst[i] = tile[c0 + i][r];
}

// ---------------------------------------------------------------------------
// flash attention: per block one (bh, 64-row q-tile); each wave 16 q-rows.
// q,k: [32][2048][64]  vt: [32][64][2048]  out: [4096][1024] bf16
__global__ __launch_bounds__(256)
void attn_fwd(const __bf16* __restrict__ q, const __bf16* __restrict__ k,
              const __bf16* __restrict__ vt, __bf16* __restrict__ out) {
    __shared__ __bf16 Ks[32][64];
    __shared__ __bf16 Vs[64][32];
    __shared__ __bf16 Ps[4][16][32];
    const int t = threadIdx.x;
    const int w = t >> 6, l = t & 63;
    const int lrow = l & 15, lhi = l >> 4;
    const int bh = blockIdx.y;
    const int q0 = blockIdx.x * 64 + w * 16;

    const __bf16* qp = q + ((size_t)bh * 2048 + q0) * 64;
    bf16x8 qf0 = *(const bf16x8*)(qp + lrow * 64 + lhi * 8);
    bf16x8 qf1 = *(const bf16x8*)(qp + lrow * 64 + 32 + lhi * 8);

    f32x4 oacc[4] = {};
    float mrow[4] = {-1e30f, -1e30f, -1e30f, -1e30f};
    float lsum[4] = {0.f, 0.f, 0.f, 0.f};

    const __bf16* kg = k + (size_t)bh * 2048 * 64;
    const __bf16* vg = vt + (size_t)bh * 64 * 2048;
    const int kr = t >> 3, kc = (t & 7) * 8;  // K tile: [32][64]
    const int vr = t >> 2, vc = (t & 3) * 8;  // Vt tile: [64][32]

    for (int kv0 = 0; kv0 < 2048; kv0 += 32) {
        load_lds16(kg + (size_t)(kv0 + kr) * 64 + kc, &Ks[kr][kc]);
        load_lds16(vg + (size_t)vr * 2048 + kv0 + vc, &Vs[vr][vc]);
        __syncthreads();

        f32x4 s0 = {}, s1 = {};
        {
            bf16x8 k00 = *(const bf16x8*)(&Ks[lrow][lhi * 8]);
            bf16x8 k01 = *(const bf16x8*)(&Ks[lrow][32 + lhi * 8]);
            bf16x8 k10 = *(const bf16x8*)(&Ks[16 + lrow][lhi * 8]);
            bf16x8 k11 = *(const bf16x8*)(&Ks[16 + lrow][32 + lhi * 8]);
            s0 = __builtin_amdgcn_mfma_f32_16x16x32_bf16(qf0, k00, s0, 0, 0, 0);
            s0 = __builtin_amdgcn_mfma_f32_16x16x32_bf16(qf1, k01, s0, 0, 0, 0);
            s1 = __builtin_amdgcn_mfma_f32_16x16x32_bf16(qf0, k10, s1, 0, 0, 0);
            s1 = __builtin_amdgcn_mfma_f32_16x16x32_bf16(qf1, k11, s1, 0, 0, 0);
        }

        #pragma unroll
        for (int r = 0; r < 4; ++r) {
            float a0 = s0[r] * SCALE, a1 = s1[r] * SCALE;
            float mx = fmaxf(a0, a1);
            mx = fmaxf(mx, __shfl_xor(mx, 1, 64));
            mx = fmaxf(mx, __shfl_xor(mx, 2, 64));
            mx = fmaxf(mx, __shfl_xor(mx, 4, 64));
            mx = fmaxf(mx, __shfl_xor(mx, 8, 64));
            float mnew = fmaxf(mrow[r], mx);
            float corr = __expf(mrow[r] - mnew);
            float p0 = __expf(a0 - mnew);
            float p1 = __expf(a1 - mnew);
            float rs = p0 + p1;
            rs += __shfl_xor(rs, 1, 64);
            rs += __shfl_xor(rs, 2, 64);
            rs += __shfl_xor(rs, 4, 64);
            rs += __shfl_xor(rs, 8, 64);
            lsum[r] = lsum[r] * corr + rs;
            mrow[r] = mnew;
            oacc[0][r] *= corr; oacc[1][r] *= corr;
            oacc[2][r] *= corr; oacc[3][r] *= corr;
            Ps[w][lhi * 4 + r][lrow] = (__bf16)p0;
            Ps[w][lhi * 4 + r][16 + lrow] = (__bf16)p1;
        }

        bf16x8 pf = *(const bf16x8*)(&Ps[w][lrow][lhi * 8]);
        #pragma unroll
        for (int dt = 0; dt < 4; ++dt) {
            bf16x8 vf = *(const bf16x8*)(&Vs[dt * 16 + lrow][lhi * 8]);
            oacc[dt] = __builtin_amdgcn_mfma_f32_16x16x32_bf16(pf, vf, oacc[dt], 0, 0, 0);
        }
        __syncthreads();
    }

    const int b = bh >> 4, h = bh & 15;
    #pragma unroll
    for (int dt = 0; dt < 4; ++dt)
        #pragma unroll
        for (int r = 0; r < 4; ++r) {
            float v = oacc[dt][r] / lsum[r];
            int row = q0 + lhi * 4 + r;
            int col = h * 64 + dt * 16 + lrow;
            out[((size_t)(b * 2048 + row)) * 1024 + col] = (__bf16)v;
        }
}

// ---------------------------------------------------------------------------
extern "C" void kernel_launch(void* const* d_in, const int* in_sizes, int n_in,
                              void* d_out, int out_size, void* d_ws, size_t ws_size,
                              hipStream_t stream) {
    const float* x      = (const float*)d_in[0];
    const float* w_qkv  = (const float*)d_in[1];
    const float* b_qkv  = (const float*)d_in[2];
    const float* w_proj = (const float*)d_in[3];
    const float* b_proj = (const float*)d_in[4];
    float* out = (float*)d_out;

    __bf16* ws     = (__bf16*)d_ws;
    __bf16* x_bf   = ws;                          // 4096*1024
    __bf16* wqkvT  = x_bf + 4096 * 1024;          // 3072*1024
    __bf16* wprojT = wqkvT + 3072 * 1024;         // 1024*1024
    __bf16* qb     = wprojT + 1024 * 1024;        // 32*2048*64
    __bf16* kb     = qb + 32 * 2048 * 64;
    __bf16* vb     = kb + 32 * 2048 * 64;
    __bf16* vtb    = vb + 32 * 2048 * 64;
    __bf16* attn   = vtb + 32 * 2048 * 64;        // 4096*1024

    cvt_x<<<4096, 256, 0, stream>>>((const float4*)x, (bf16x4*)x_bf, 4096 * 1024 / 4);
    tconv<<<dim3(96, 32), dim3(32, 8), 0, stream>>>(w_qkv, wqkvT, 1024, 3072);
    tconv<<<dim3(32, 32), dim3(32, 8), 0, stream>>>(w_proj, wprojT, 1024, 1024);
    gemm128<0><<<dim3(24, 32), 256, 0, stream>>>(x_bf, wqkvT, b_qkv, qb, 4096, 3072, 1024);
    vtrans<<<dim3(32, 32), 256, 0, stream>>>(vb, vtb);
    attn_fwd<<<dim3(32, 32), 256, 0, stream>>>(qb, kb, vtb, attn);
    gemm128<1><<<dim3(8, 32), 256, 0, stream>>>(attn, wprojT, b_proj, out, 4096, 1024, 1024);
}

// Round 2
// 221.978 us; speedup vs baseline: 1.5671x; 1.5671x over previous
//
#include <hip/hip_runtime.h>
#include <hip/hip_bf16.h>
#include <stdint.h>

typedef __attribute__((ext_vector_type(8))) __bf16 bf16x8;
typedef __attribute__((ext_vector_type(4))) __bf16 bf16x4;
typedef __attribute__((ext_vector_type(4))) float f32x4;

#define AS1 __attribute__((address_space(1)))
#define AS3 __attribute__((address_space(3)))

__device__ __forceinline__ void load_lds16(const void* g, void* l) {
    __builtin_amdgcn_global_load_lds((const AS1 void*)g, (AS3 void*)l, 16, 0, 0);
}

constexpr float QSCALE = 0.18033688011112042f;  // 64^-0.5 * log2(e)

// sigma: storage position of kv (0..31) within a 32-column block of Vt,
// chosen so the PV B-operand slots match the P-register slots (phi mapping).
__device__ __forceinline__ int sigma32(int kv) {
    return (kv < 16) ? ((kv >> 2) * 8 + (kv & 3))
                     : (((kv - 16) >> 2) * 8 + 4 + ((kv - 16) & 3));
}

// ---------------------------------------------------------------------------
__global__ void cvt_x(const float4* __restrict__ x, bf16x4* __restrict__ o, int n4) {
    int i = blockIdx.x * blockDim.x + threadIdx.x;
    if (i >= n4) return;
    float4 v = x[i];
    bf16x4 r;
    r[0] = (__bf16)v.x; r[1] = (__bf16)v.y; r[2] = (__bf16)v.z; r[3] = (__bf16)v.w;
    o[i] = r;
}

// ---------------------------------------------------------------------------
__global__ void tconv(const float* __restrict__ src, __bf16* __restrict__ dst,
                      int R, int C) {
    __shared__ float tile[32][33];
    int c0 = blockIdx.x * 32, r0 = blockIdx.y * 32;
    int tx = threadIdx.x, ty = threadIdx.y;  // 32 x 8
    #pragma unroll
    for (int i = 0; i < 32; i += 8)
        tile[ty + i][tx] = src[(size_t)(r0 + ty + i) * C + c0 + tx];
    __syncthreads();
    #pragma unroll
    for (int i = 0; i < 32; i += 8)
        dst[(size_t)(c0 + ty + i) * R + r0 + tx] = (__bf16)tile[tx][ty + i];
}

// ---------------------------------------------------------------------------
// 128x128 bf16 GEMM, Bt is [N][K]. C = A @ Bt^T + bias.
// MODE 0: scatter Q (pre-scaled by QSCALE), K into [bh][n][d]; V transposed+
//         sigma-interleaved into Vt [bh][d][n'].  outp = q base.
// MODE 1: plain fp32 [M][Nn] output
template <int MODE>
__global__ __launch_bounds__(256)
void gemm128(const __bf16* __restrict__ A, const __bf16* __restrict__ Bt,
             const float* __restrict__ bias, void* __restrict__ outp,
             int M, int Nn, int K) {
    __shared__ __bf16 As[128][32];
    __shared__ __bf16 Bs[128][32];
    const int t = threadIdx.x;
    const int w = t >> 6, l = t & 63;
    const int lrow = l & 15, lhi = l >> 4;
    const int wr = (w >> 1) * 64, wc = (w & 1) * 64;
    const int m0 = blockIdx.y * 128, n0 = blockIdx.x * 128;

    f32x4 acc[4][4] = {};

    const int sr = t >> 2, sc = (t & 3) * 8;
    const __bf16* ag = A + (size_t)(m0 + sr) * K + sc;
    const __bf16* bg = Bt + (size_t)(n0 + sr) * K + sc;

    for (int kt = 0; kt < K; kt += 32) {
        load_lds16(ag, &As[sr][sc]);
        load_lds16(ag + (size_t)64 * K, &As[64 + sr][sc]);
        load_lds16(bg, &Bs[sr][sc]);
        load_lds16(bg + (size_t)64 * K, &Bs[64 + sr][sc]);
        ag += 32; bg += 32;
        __syncthreads();
        bf16x8 af[4], bfv[4];
        #pragma unroll
        for (int i = 0; i < 4; ++i)
            af[i] = *(const bf16x8*)(&As[wr + i * 16 + lrow][lhi * 8]);
        #pragma unroll
        for (int j = 0; j < 4; ++j)
            bfv[j] = *(const bf16x8*)(&Bs[wc + j * 16 + lrow][lhi * 8]);
        #pragma unroll
        for (int i = 0; i < 4; ++i)
            #pragma unroll
            for (int j = 0; j < 4; ++j)
                acc[i][j] = __builtin_amdgcn_mfma_f32_16x16x32_bf16(
                    af[i], bfv[j], acc[i][j], 0, 0, 0);
        __syncthreads();
    }

    #pragma unroll
    for (int i = 0; i < 4; ++i)
        #pragma unroll
        for (int j = 0; j < 4; ++j)
            #pragma unroll
            for (int r = 0; r < 4; ++r) {
                int row = m0 + wr + i * 16 + lhi * 4 + r;
                int col = n0 + wc + j * 16 + lrow;
                float val = acc[i][j][r] + bias[col];
                if (MODE == 0) {
                    int which = col >> 10;          // 0=q 1=k 2=v
                    int h = (col >> 6) & 15;
                    int d = col & 63;
                    int b = row >> 11;
                    int n = row & 2047;
                    int bh = (b << 4) + h;
                    if (which == 2) {
                        // Vt [bh][d][ (n&~31) + sigma(n&31) ]
                        ((__bf16*)outp)[(size_t)2 * (32 * 2048 * 64) +
                                        ((size_t)bh * 64 + d) * 2048 +
                                        (n & ~31) + sigma32(n & 31)] = (__bf16)val;
                    } else {
                        if (which == 0) val *= QSCALE;
                        ((__bf16*)outp)[(size_t)which * (32 * 2048 * 64) +
                                        ((size_t)bh * 2048 + n) * 64 + d] = (__bf16)val;
                    }
                } else {
                    ((float*)outp)[(size_t)row * Nn + col] = val;
                }
            }
}

// ---------------------------------------------------------------------------
// flash attention, swapped-QK^T, in-register P, swizzled K/V LDS, KVBLK=64.
// q,k: [32][2048][64] (q pre-scaled)   vt: [32][64][2048] sigma-interleaved
// out: [4096][1024] bf16
__global__ __launch_bounds__(256)
void attn_fwd(const __bf16* __restrict__ q, const __bf16* __restrict__ k,
              const __bf16* __restrict__ vt, __bf16* __restrict__ out) {
    __shared__ __bf16 KsV[2][64][64];
    __shared__ __bf16 VsV[2][64][64];
    char* ksB = (char*)KsV;
    char* vsB = (char*)VsV;

    const int t = threadIdx.x;
    const int w = t >> 6, l = t & 63;
    const int lrow = l & 15, lhi = l >> 4;
    const int bh = blockIdx.y;
    const int q0 = blockIdx.x * 64 + w * 16;

    // Q fragment (B-operand): lane holds Q[q=lrow][d-slots], halves d0-31/32-63
    const __bf16* qp = q + ((size_t)bh * 2048 + q0) * 64;
    bf16x8 qf0 = *(const bf16x8*)(qp + lrow * 64 + lhi * 8);
    bf16x8 qf1 = *(const bf16x8*)(qp + lrow * 64 + 32 + lhi * 8);

    f32x4 oacc[4] = {};
    float mrun = -1e30f, lsum = 0.f;

    const __bf16* kg = k + (size_t)bh * 2048 * 64;
    const __bf16* vg = vt + (size_t)bh * 64 * 2048;

    // staging: row sr (0..31) + chunk row+32; pre-swizzled source slot
    const int sr = t >> 3;
    const int sw8 = ((t & 7) ^ (sr & 7)) * 8;  // elems

    const int rsw = (lrow & 7) << 4;  // read-side row-XOR (bytes)

    // prologue: stage tile 0 into buf 0
    {
        char* kd = ksB + t * 16;
        char* vd = vsB + t * 16;
        load_lds16(kg + (size_t)sr * 64 + sw8, kd);
        load_lds16(kg + (size_t)(32 + sr) * 64 + sw8, kd + 4096);
        load_lds16(vg + (size_t)sr * 2048 + sw8, vd);
        load_lds16(vg + (size_t)(32 + sr) * 2048 + sw8, vd + 4096);
    }

    int cur = 0;
    for (int kv0 = 0; kv0 < 2048; kv0 += 64) {
        __syncthreads();  // drains own vmcnt -> buf[cur] ready for all waves
        if (kv0 + 64 < 2048) {
            char* kd = ksB + (cur ^ 1) * 8192 + t * 16;
            char* vd = vsB + (cur ^ 1) * 8192 + t * 16;
            load_lds16(kg + (size_t)(kv0 + 64 + sr) * 64 + sw8, kd);
            load_lds16(kg + (size_t)(kv0 + 96 + sr) * 64 + sw8, kd + 4096);
            load_lds16(vg + (size_t)sr * 2048 + kv0 + 64 + sw8, vd);
            load_lds16(vg + (size_t)(32 + sr) * 2048 + kv0 + 64 + sw8, vd + 4096);
        }
        const char* kb = ksB + cur * 8192 + lrow * 128;
        const char* vb = vsB + cur * 8192 + lrow * 128;

        // QK^T swapped: S^T[kv][q], 4 tiles of 16 kv
        f32x4 s0 = {}, s1 = {}, s2 = {}, s3 = {};
        {
            bf16x8 kf;
            kf = *(const bf16x8*)(kb + (((0 + lhi) << 4) ^ rsw));
            s0 = __builtin_amdgcn_mfma_f32_16x16x32_bf16(kf, qf0, s0, 0, 0, 0);
            kf = *(const bf16x8*)(kb + (((4 + lhi) << 4) ^ rsw));
            s0 = __builtin_amdgcn_mfma_f32_16x16x32_bf16(kf, qf1, s0, 0, 0, 0);
            kf = *(const bf16x8*)(kb + 2048 + (((0 + lhi) << 4) ^ rsw));
            s1 = __builtin_amdgcn_mfma_f32_16x16x32_bf16(kf, qf0, s1, 0, 0, 0);
            kf = *(const bf16x8*)(kb + 2048 + (((4 + lhi) << 4) ^ rsw));
            s1 = __builtin_amdgcn_mfma_f32_16x16x32_bf16(kf, qf1, s1, 0, 0, 0);
            kf = *(const bf16x8*)(kb + 4096 + (((0 + lhi) << 4) ^ rsw));
            s2 = __builtin_amdgcn_mfma_f32_16x16x32_bf16(kf, qf0, s2, 0, 0, 0);
            kf = *(const bf16x8*)(kb + 4096 + (((4 + lhi) << 4) ^ rsw));
            s2 = __builtin_amdgcn_mfma_f32_16x16x32_bf16(kf, qf1, s2, 0, 0, 0);
            kf = *(const bf16x8*)(kb + 6144 + (((0 + lhi) << 4) ^ rsw));
            s3 = __builtin_amdgcn_mfma_f32_16x16x32_bf16(kf, qf0, s3, 0, 0, 0);
            kf = *(const bf16x8*)(kb + 6144 + (((4 + lhi) << 4) ^ rsw));
            s3 = __builtin_amdgcn_mfma_f32_16x16x32_bf16(kf, qf1, s3, 0, 0, 0);
        }

        // in-register softmax: lane owns 16 scores of q-row (q=lrow), exp2 domain
        float tm;
        {
            float t0 = fmaxf(fmaxf(s0[0], s0[1]), fmaxf(s0[2], s0[3]));
            float t1 = fmaxf(fmaxf(s1[0], s1[1]), fmaxf(s1[2], s1[3]));
            float t2 = fmaxf(fmaxf(s2[0], s2[1]), fmaxf(s2[2], s2[3]));
            float t3 = fmaxf(fmaxf(s3[0], s3[1]), fmaxf(s3[2], s3[3]));
            tm = fmaxf(fmaxf(t0, t1), fmaxf(t2, t3));
        }
        tm = fmaxf(tm, __shfl_xor(tm, 16, 64));
        tm = fmaxf(tm, __shfl_xor(tm, 32, 64));
        if (!__all(tm <= mrun + 8.0f)) {  // defer-max (T13)
            float mn = fmaxf(mrun, tm);
            float corr = __builtin_amdgcn_exp2f(mrun - mn);
            lsum *= corr;
            #pragma unroll
            for (int dt = 0; dt < 4; ++dt)
                #pragma unroll
                for (int r = 0; r < 4; ++r) oacc[dt][r] *= corr;
            mrun = mn;
        }
        float p[16];
        #pragma unroll
        for (int r = 0; r < 4; ++r) {
            p[r]      = __builtin_amdgcn_exp2f(s0[r] - mrun);
            p[4 + r]  = __builtin_amdgcn_exp2f(s1[r] - mrun);
            p[8 + r]  = __builtin_amdgcn_exp2f(s2[r] - mrun);
            p[12 + r] = __builtin_amdgcn_exp2f(s3[r] - mrun);
        }
        float rs = 0.f;
        #pragma unroll
        for (int j = 0; j < 16; ++j) rs += p[j];
        rs += __shfl_xor(rs, 16, 64);
        rs += __shfl_xor(rs, 32, 64);
        lsum += rs;

        // pack P into A... B-operand slots matching phi (kv = 4*hi+j / 16+4*hi+j)
        bf16x8 pf0, pf1;
        #pragma unroll
        for (int j = 0; j < 4; ++j) {
            pf0[j] = (__bf16)p[j];       pf0[4 + j] = (__bf16)p[4 + j];
            pf1[j] = (__bf16)p[8 + j];   pf1[4 + j] = (__bf16)p[12 + j];
        }

        // PV: O^T[d][q] = mfma(A=V'(phi), B=P(phi))
        #pragma unroll
        for (int dt = 0; dt < 4; ++dt) {
            bf16x8 vf;
            vf = *(const bf16x8*)(vb + dt * 2048 + (((0 + lhi) << 4) ^ rsw));
            oacc[dt] = __builtin_amdgcn_mfma_f32_16x16x32_bf16(vf, pf0, oacc[dt], 0, 0, 0);
            vf = *(const bf16x8*)(vb + dt * 2048 + (((4 + lhi) << 4) ^ rsw));
            oacc[dt] = __builtin_amdgcn_mfma_f32_16x16x32_bf16(vf, pf1, oacc[dt], 0, 0, 0);
        }
        cur ^= 1;
    }

    // epilogue: oacc[dt][r] = O^T[d=dt*16+lhi*4+r][q=lrow]
    float inv = __builtin_amdgcn_rcpf(lsum);
    const int b = bh >> 4, h = bh & 15;
    __bf16* orow = out + ((size_t)(b * 2048 + q0 + lrow)) * 1024 + h * 64;
    #pragma unroll
    for (int dt = 0; dt < 4; ++dt) {
        bf16x4 ov;
        #pragma unroll
        for (int r = 0; r < 4; ++r) ov[r] = (__bf16)(oacc[dt][r] * inv);
        *(bf16x4*)(orow + dt * 16 + lhi * 4) = ov;
    }
}

// ---------------------------------------------------------------------------
extern "C" void kernel_launch(void* const* d_in, const int* in_sizes, int n_in,
                              void* d_out, int out_size, void* d_ws, size_t ws_size,
                              hipStream_t stream) {
    const float* x      = (const float*)d_in[0];
    const float* w_qkv  = (const float*)d_in[1];
    const float* b_qkv  = (const float*)d_in[2];
    const float* w_proj = (const float*)d_in[3];
    const float* b_proj = (const float*)d_in[4];
    float* out = (float*)d_out;

    __bf16* ws     = (__bf16*)d_ws;
    __bf16* x_bf   = ws;                          // 4096*1024
    __bf16* wqkvT  = x_bf + 4096 * 1024;          // 3072*1024
    __bf16* wprojT = wqkvT + 3072 * 1024;         // 1024*1024
    __bf16* qb     = wprojT + 1024 * 1024;        // 32*2048*64
    __bf16* kb     = qb + 32 * 2048 * 64;
    __bf16* vtb    = kb + 32 * 2048 * 64;         // sigma-interleaved V^T
    __bf16* attn   = vtb + 32 * 2048 * 64;        // 4096*1024

    cvt_x<<<4096, 256, 0, stream>>>((const float4*)x, (bf16x4*)x_bf, 4096 * 1024 / 4);
    tconv<<<dim3(96, 32), dim3(32, 8), 0, stream>>>(w_qkv, wqkvT, 1024, 3072);
    tconv<<<dim3(32, 32), dim3(32, 8), 0, stream>>>(w_proj, wprojT, 1024, 1024);
    gemm128<0><<<dim3(24, 32), 256, 0, stream>>>(x_bf, wqkvT, b_qkv, qb, 4096, 3072, 1024);
    attn_fwd<<<dim3(32, 32), 256, 0, stream>>>(qb, kb, vtb, attn);
    gemm128<1><<<dim3(8, 32), 256, 0, stream>>>(attn, wprojT, b_proj, out, 4096, 1024, 1024);
}

// Round 4
// 218.072 us; speedup vs baseline: 1.5952x; 1.0179x over previous
//
#include <hip/hip_runtime.h>
#include <hip/hip_bf16.h>
#include <stdint.h>

typedef __attribute__((ext_vector_type(8))) __bf16 bf16x8;
typedef __attribute__((ext_vector_type(4))) __bf16 bf16x4;
typedef __attribute__((ext_vector_type(4))) float f32x4;

#define AS1 __attribute__((address_space(1)))
#define AS3 __attribute__((address_space(3)))

__device__ __forceinline__ void load_lds16(const void* g, void* l) {
    __builtin_amdgcn_global_load_lds((const AS1 void*)g, (AS3 void*)l, 16, 0, 0);
}

__device__ __forceinline__ float m3(float a, float b, float c) {
    return fmaxf(fmaxf(a, b), c);  // clang fuses to v_max3_f32
}

constexpr float QSCALE = 0.18033688011112042f;  // 64^-0.5 * log2(e)

// sigma: storage position of kv (0..31) within a 32-column block of Vt,
// chosen so the PV B-operand slots match the P-register slots (phi mapping).
__device__ __forceinline__ int sigma32(int kv) {
    return (kv < 16) ? ((kv >> 2) * 8 + (kv & 3))
                     : (((kv - 16) >> 2) * 8 + 4 + ((kv - 16) & 3));
}

// ---------------------------------------------------------------------------
__global__ void cvt_x(const float4* __restrict__ x, bf16x4* __restrict__ o, int n4) {
    int i = blockIdx.x * blockDim.x + threadIdx.x;
    if (i >= n4) return;
    float4 v = x[i];
    bf16x4 r;
    r[0] = (__bf16)v.x; r[1] = (__bf16)v.y; r[2] = (__bf16)v.z; r[3] = (__bf16)v.w;
    o[i] = r;
}

// ---------------------------------------------------------------------------
__global__ void tconv(const float* __restrict__ src, __bf16* __restrict__ dst,
                      int R, int C) {
    __shared__ float tile[32][33];
    int c0 = blockIdx.x * 32, r0 = blockIdx.y * 32;
    int tx = threadIdx.x, ty = threadIdx.y;  // 32 x 8
    #pragma unroll
    for (int i = 0; i < 32; i += 8)
        tile[ty + i][tx] = src[(size_t)(r0 + ty + i) * C + c0 + tx];
    __syncthreads();
    #pragma unroll
    for (int i = 0; i < 32; i += 8)
        dst[(size_t)(c0 + ty + i) * R + r0 + tx] = (__bf16)tile[tx][ty + i];
}

// ---------------------------------------------------------------------------
// 128x128 bf16 GEMM, Bt is [N][K]. C = A @ Bt^T + bias.
// MODE 0: scatter Q (pre-scaled by QSCALE), K into [bh][n][d]; V transposed+
//         sigma-interleaved into Vt [bh][d][n'].  outp = q base.
// MODE 1: plain fp32 [M][Nn] output
template <int MODE>
__global__ __launch_bounds__(256)
void gemm128(const __bf16* __restrict__ A, const __bf16* __restrict__ Bt,
             const float* __restrict__ bias, void* __restrict__ outp,
             int M, int Nn, int K) {
    __shared__ __bf16 As[128][32];
    __shared__ __bf16 Bs[128][32];
    const int t = threadIdx.x;
    const int w = t >> 6, l = t & 63;
    const int lrow = l & 15, lhi = l >> 4;
    const int wr = (w >> 1) * 64, wc = (w & 1) * 64;
    const int m0 = blockIdx.y * 128, n0 = blockIdx.x * 128;

    f32x4 acc[4][4] = {};

    const int sr = t >> 2, sc = (t & 3) * 8;
    const __bf16* ag = A + (size_t)(m0 + sr) * K + sc;
    const __bf16* bg = Bt + (size_t)(n0 + sr) * K + sc;

    for (int kt = 0; kt < K; kt += 32) {
        load_lds16(ag, &As[sr][sc]);
        load_lds16(ag + (size_t)64 * K, &As[64 + sr][sc]);
        load_lds16(bg, &Bs[sr][sc]);
        load_lds16(bg + (size_t)64 * K, &Bs[64 + sr][sc]);
        ag += 32; bg += 32;
        __syncthreads();
        bf16x8 af[4], bfv[4];
        #pragma unroll
        for (int i = 0; i < 4; ++i)
            af[i] = *(const bf16x8*)(&As[wr + i * 16 + lrow][lhi * 8]);
        #pragma unroll
        for (int j = 0; j < 4; ++j)
            bfv[j] = *(const bf16x8*)(&Bs[wc + j * 16 + lrow][lhi * 8]);
        #pragma unroll
        for (int i = 0; i < 4; ++i)
            #pragma unroll
            for (int j = 0; j < 4; ++j)
                acc[i][j] = __builtin_amdgcn_mfma_f32_16x16x32_bf16(
                    af[i], bfv[j], acc[i][j], 0, 0, 0);
        __syncthreads();
    }

    #pragma unroll
    for (int i = 0; i < 4; ++i)
        #pragma unroll
        for (int j = 0; j < 4; ++j)
            #pragma unroll
            for (int r = 0; r < 4; ++r) {
                int row = m0 + wr + i * 16 + lhi * 4 + r;
                int col = n0 + wc + j * 16 + lrow;
                float val = acc[i][j][r] + bias[col];
                if (MODE == 0) {
                    int which = col >> 10;          // 0=q 1=k 2=v
                    int h = (col >> 6) & 15;
                    int d = col & 63;
                    int b = row >> 11;
                    int n = row & 2047;
                    int bh = (b << 4) + h;
                    if (which == 2) {
                        ((__bf16*)outp)[(size_t)2 * (32 * 2048 * 64) +
                                        ((size_t)bh * 64 + d) * 2048 +
                                        (n & ~31) + sigma32(n & 31)] = (__bf16)val;
                    } else {
                        if (which == 0) val *= QSCALE;
                        ((__bf16*)outp)[(size_t)which * (32 * 2048 * 64) +
                                        ((size_t)bh * 2048 + n) * 64 + d] = (__bf16)val;
                    }
                } else {
                    ((float*)outp)[(size_t)row * Nn + col] = val;
                }
            }
}

// ---------------------------------------------------------------------------
// flash attention, swapped-QK^T, in-register P, swizzled K/V LDS, KVBLK=64.
// Each wave owns 32 q-rows (2 groups of 16 sharing K/V fragments).
// q,k: [32][2048][64] (q pre-scaled)   vt: [32][64][2048] sigma-interleaved
// out: [4096][1024] bf16
__global__ __launch_bounds__(256)
void attn_fwd(const __bf16* __restrict__ q, const __bf16* __restrict__ k,
              const __bf16* __restrict__ vt, __bf16* __restrict__ out) {
    __shared__ __bf16 KsV[2][64][64];
    __shared__ __bf16 VsV[2][64][64];
    char* ksB = (char*)KsV;
    char* vsB = (char*)VsV;

    const int t = threadIdx.x;
    const int w = t >> 6, l = t & 63;
    const int lrow = l & 15, lhi = l >> 4;
    const int bh = blockIdx.y;
    const int q0 = blockIdx.x * 128 + w * 32;

    // Q fragments (B-operand): group A = rows q0..q0+15, group B = +16
    const __bf16* qp = q + ((size_t)bh * 2048 + q0) * 64;
    bf16x8 qfA0 = *(const bf16x8*)(qp + lrow * 64 + lhi * 8);
    bf16x8 qfA1 = *(const bf16x8*)(qp + lrow * 64 + 32 + lhi * 8);
    bf16x8 qfB0 = *(const bf16x8*)(qp + (16 + lrow) * 64 + lhi * 8);
    bf16x8 qfB1 = *(const bf16x8*)(qp + (16 + lrow) * 64 + 32 + lhi * 8);

    f32x4 oA[4] = {}, oB[4] = {};
    float mA = -1e30f, mB = -1e30f;
    float lA = 0.f, lB = 0.f;  // per-lane partial sums

    const __bf16* kg = k + (size_t)bh * 2048 * 64;
    const __bf16* vg = vt + (size_t)bh * 64 * 2048;

    const int sr = t >> 3;
    const int sw8 = ((t & 7) ^ (sr & 7)) * 8;   // pre-swizzled source chunk
    const int rsw = (lrow & 7) << 4;            // read-side row-XOR (bytes)

    // prologue: stage tile 0 into buf 0
    {
        char* kd = ksB + t * 16;
        char* vd = vsB + t * 16;
        load_lds16(kg + (size_t)sr * 64 + sw8, kd);
        load_lds16(kg + (size_t)(32 + sr) * 64 + sw8, kd + 4096);
        load_lds16(vg + (size_t)sr * 2048 + sw8, vd);
        load_lds16(vg + (size_t)(32 + sr) * 2048 + sw8, vd + 4096);
    }

    // strength-reduced next-tile staging pointers
    const __bf16* kst  = kg + (size_t)(64 + sr) * 64 + sw8;
    const __bf16* kst2 = kst + 32 * 64;
    const __bf16* vst  = vg + (size_t)sr * 2048 + 64 + sw8;
    const __bf16* vst2 = vst + 32 * 2048;

    int cur = 0;
    for (int kv0 = 0; kv0 < 2048; kv0 += 64) {
        __syncthreads();  // compiler drains vmcnt before barrier -> buf[cur] ready
        if (kv0 + 64 < 2048) {
            char* kd = ksB + (cur ^ 1) * 8192 + t * 16;
            char* vd = vsB + (cur ^ 1) * 8192 + t * 16;
            load_lds16(kst, kd);
            load_lds16(kst2, kd + 4096);
            load_lds16(vst, vd);
            load_lds16(vst2, vd + 4096);
            kst += 4096; kst2 += 4096; vst += 64; vst2 += 64;
        }
        const char* kb = ksB + cur * 8192 + lrow * 128;
        const char* vb = vsB + cur * 8192 + lrow * 128;
        const int o0 = (lhi << 4) ^ rsw;
        const int o4 = ((4 + lhi) << 4) ^ rsw;

        // QK^T swapped: S^T[kv][q]; K fragments shared between q-groups
        f32x4 sA0 = {}, sA1 = {}, sA2 = {}, sA3 = {};
        f32x4 sB0 = {}, sB1 = {}, sB2 = {}, sB3 = {};
        __builtin_amdgcn_s_setprio(1);
        {
            bf16x8 kf0, kf1;
#define QK_GROUP(SA, SB, BASE)                                                 \
            kf0 = *(const bf16x8*)(kb + (BASE) + o0);                          \
            kf1 = *(const bf16x8*)(kb + (BASE) + o4);                          \
            SA = __builtin_amdgcn_mfma_f32_16x16x32_bf16(kf0, qfA0, SA, 0, 0, 0); \
            SA = __builtin_amdgcn_mfma_f32_16x16x32_bf16(kf1, qfA1, SA, 0, 0, 0); \
            SB = __builtin_amdgcn_mfma_f32_16x16x32_bf16(kf0, qfB0, SB, 0, 0, 0); \
            SB = __builtin_amdgcn_mfma_f32_16x16x32_bf16(kf1, qfB1, SB, 0, 0, 0);
            QK_GROUP(sA0, sB0, 0)
            QK_GROUP(sA1, sB1, 2048)
            QK_GROUP(sA2, sB2, 4096)
            QK_GROUP(sA3, sB3, 6144)
#undef QK_GROUP
        }
        __builtin_amdgcn_s_setprio(0);

        // ---- softmax (exp2 domain), per-lane partials, defer-max ----
        float u0 = m3(sA0[0], sA0[1], sA0[2]);
        float u1 = m3(sA0[3], sA1[0], sA1[1]);
        float u2 = m3(sA1[2], sA1[3], sA2[0]);
        float u3 = m3(sA2[1], sA2[2], sA2[3]);
        float u4 = m3(sA3[0], sA3[1], sA3[2]);
        float tmA = fmaxf(m3(u0, u1, u2), m3(u3, u4, sA3[3]));
        float v0 = m3(sB0[0], sB0[1], sB0[2]);
        float v1 = m3(sB0[3], sB1[0], sB1[1]);
        float v2 = m3(sB1[2], sB1[3], sB2[0]);
        float v3 = m3(sB2[1], sB2[2], sB2[3]);
        float v4 = m3(sB3[0], sB3[1], sB3[2]);
        float tmB = fmaxf(m3(v0, v1, v2), m3(v3, v4, sB3[3]));
        tmA = fmaxf(tmA, __shfl_xor(tmA, 16, 64));
        tmA = fmaxf(tmA, __shfl_xor(tmA, 32, 64));
        tmB = fmaxf(tmB, __shfl_xor(tmB, 16, 64));
        tmB = fmaxf(tmB, __shfl_xor(tmB, 32, 64));
        if (!__all(tmA <= mA + 8.0f && tmB <= mB + 8.0f)) {
            float mnA = fmaxf(mA, tmA), mnB = fmaxf(mB, tmB);
            float cA = __builtin_amdgcn_exp2f(mA - mnA);
            float cB = __builtin_amdgcn_exp2f(mB - mnB);
            lA *= cA; lB *= cB;
            #pragma unroll
            for (int dt = 0; dt < 4; ++dt)
                #pragma unroll
                for (int r = 0; r < 4; ++r) { oA[dt][r] *= cA; oB[dt][r] *= cB; }
            mA = mnA; mB = mnB;
        }
        float pA[16], pB[16];
        #pragma unroll
        for (int r = 0; r < 4; ++r) {
            pA[r]      = __builtin_amdgcn_exp2f(sA0[r] - mA);
            pA[4 + r]  = __builtin_amdgcn_exp2f(sA1[r] - mA);
            pA[8 + r]  = __builtin_amdgcn_exp2f(sA2[r] - mA);
            pA[12 + r] = __builtin_amdgcn_exp2f(sA3[r] - mA);
            pB[r]      = __builtin_amdgcn_exp2f(sB0[r] - mB);
            pB[4 + r]  = __builtin_amdgcn_exp2f(sB1[r] - mB);
            pB[8 + r]  = __builtin_amdgcn_exp2f(sB2[r] - mB);
            pB[12 + r] = __builtin_amdgcn_exp2f(sB3[r] - mB);
        }
        float rsA = 0.f, rsB = 0.f;
        #pragma unroll
        for (int j = 0; j < 16; ++j) { rsA += pA[j]; rsB += pB[j]; }
        lA += rsA; lB += rsB;

        bf16x8 pfA0, pfA1, pfB0, pfB1;
        #pragma unroll
        for (int j = 0; j < 8; ++j) {
            pfA0[j] = (__bf16)pA[j]; pfA1[j] = (__bf16)pA[8 + j];
            pfB0[j] = (__bf16)pB[j]; pfB1[j] = (__bf16)pB[8 + j];
        }

        // PV: O^T[d][q]; V fragments shared between q-groups
        __builtin_amdgcn_s_setprio(1);
        #pragma unroll
        for (int dt = 0; dt < 4; ++dt) {
            bf16x8 vf0 = *(const bf16x8*)(vb + dt * 2048 + o0);
            bf16x8 vf1 = *(const bf16x8*)(vb + dt * 2048 + o4);
            oA[dt] = __builtin_amdgcn_mfma_f32_16x16x32_bf16(vf0, pfA0, oA[dt], 0, 0, 0);
            oA[dt] = __builtin_amdgcn_mfma_f32_16x16x32_bf16(vf1, pfA1, oA[dt], 0, 0, 0);
            oB[dt] = __builtin_amdgcn_mfma_f32_16x16x32_bf16(vf0, pfB0, oB[dt], 0, 0, 0);
            oB[dt] = __builtin_amdgcn_mfma_f32_16x16x32_bf16(vf1, pfB1, oB[dt], 0, 0, 0);
        }
        __builtin_amdgcn_s_setprio(0);
        cur ^= 1;
    }

    // cross-lane lsum reduce (lanes lrow, lrow+16, +32, +48 share a q-row)
    lA += __shfl_xor(lA, 16, 64); lA += __shfl_xor(lA, 32, 64);
    lB += __shfl_xor(lB, 16, 64); lB += __shfl_xor(lB, 32, 64);
    float invA = __builtin_amdgcn_rcpf(lA);
    float invB = __builtin_amdgcn_rcpf(lB);

    const int b = bh >> 4, h = bh & 15;
    __bf16* orowA = out + ((size_t)(b * 2048 + q0 + lrow)) * 1024 + h * 64;
    __bf16* orowB = out + ((size_t)(b * 2048 + q0 + 16 + lrow)) * 1024 + h * 64;
    #pragma unroll
    for (int dt = 0; dt < 4; ++dt) {
        bf16x4 ovA, ovB;
        #pragma unroll
        for (int r = 0; r < 4; ++r) {
            ovA[r] = (__bf16)(oA[dt][r] * invA);
            ovB[r] = (__bf16)(oB[dt][r] * invB);
        }
        *(bf16x4*)(orowA + dt * 16 + lhi * 4) = ovA;
        *(bf16x4*)(orowB + dt * 16 + lhi * 4) = ovB;
    }
}

// ---------------------------------------------------------------------------
extern "C" void kernel_launch(void* const* d_in, const int* in_sizes, int n_in,
                              void* d_out, int out_size, void* d_ws, size_t ws_size,
                              hipStream_t stream) {
    const float* x      = (const float*)d_in[0];
    const float* w_qkv  = (const float*)d_in[1];
    const float* b_qkv  = (const float*)d_in[2];
    const float* w_proj = (const float*)d_in[3];
    const float* b_proj = (const float*)d_in[4];
    float* out = (float*)d_out;

    __bf16* ws     = (__bf16*)d_ws;
    __bf16* x_bf   = ws;                          // 4096*1024
    __bf16* wqkvT  = x_bf + 4096 * 1024;          // 3072*1024
    __bf16* wprojT = wqkvT + 3072 * 1024;         // 1024*1024
    __bf16* qb     = wprojT + 1024 * 1024;        // 32*2048*64
    __bf16* kb     = qb + 32 * 2048 * 64;
    __bf16* vtb    = kb + 32 * 2048 * 64;         // sigma-interleaved V^T
    __bf16* attn   = vtb + 32 * 2048 * 64;        // 4096*1024

    cvt_x<<<4096, 256, 0, stream>>>((const float4*)x, (bf16x4*)x_bf, 4096 * 1024 / 4);
    tconv<<<dim3(96, 32), dim3(32, 8), 0, stream>>>(w_qkv, wqkvT, 1024, 3072);
    tconv<<<dim3(32, 32), dim3(32, 8), 0, stream>>>(w_proj, wprojT, 1024, 1024);
    gemm128<0><<<dim3(24, 32), 256, 0, stream>>>(x_bf, wqkvT, b_qkv, qb, 4096, 3072, 1024);
    attn_fwd<<<dim3(16, 32), 256, 0, stream>>>(qb, kb, vtb, attn);
    gemm128<1><<<dim3(8, 32), 256, 0, stream>>>(attn, wprojT, b_proj, out, 4096, 1024, 1024);
}